// Round 16
// baseline (111.466 us; speedup 1.0000x reference)
//
#include <hip/hip_runtime.h>
#include <hip/hip_bf16.h>

// SDPA, causal, b=16 t=2048 d=64. Outputs FP32: d_out = [ out | sm_qk ].
// R16 = R15 with EQUAL-LENGTH block pairing: CU gets (qb=c, qb=c^1) instead
// of (c, 31-c). Rounds are latency-bound (all util ~10%) -> co-resident
// blocks' rounds overlap; wall = max(len) not sum. Old pairing: worst CU =
// 64 solo rounds (qb=31 after qb=0 exits). New: worst CU = ~32 concurrent
// rounds. Per-CU stores also become exactly uniform (64 tiles/CU).
// R15 structure: 8-wave blocks, wave w owns rows (w&3)*16..+16 and S-cols
// 32(w>>2)..+32; T15 PV(kt-1)||QKT(kt) pipeline; K/V role-split staging;
// lgkm-only barriers; Q-side-compensated QK^T in phase 2.

#define BATCHES 16
#define SEQ 2048
#define DIM 64
#define QB 64
#define KT 64
#define NQB (SEQ / QB) /* 32 */
#define KLD 72
#define VLD 72
#define PBLD 72

#define BAR() do { asm volatile("s_waitcnt lgkmcnt(0)" ::: "memory"); \
                   __builtin_amdgcn_s_barrier(); } while (0)

typedef __attribute__((ext_vector_type(8))) short bf16x8;
typedef __attribute__((ext_vector_type(4))) short short4v;
typedef __attribute__((ext_vector_type(4))) float f32x4;

static __device__ __forceinline__ short f2bf(float f) {
    return __builtin_bit_cast(short, __float2bfloat16(f));
}
static __device__ __forceinline__ float bf2f(short s) {
    unsigned int u = ((unsigned int)(unsigned short)s) << 16;
    return __builtin_bit_cast(float, u);
}
static __device__ __forceinline__ void split8(f32x4 a, f32x4 b, float sc,
                                              bf16x8& hh, bf16x8& ll) {
#pragma unroll
    for (int e = 0; e < 4; ++e) {
        float x = a[e] * sc; short hb = f2bf(x);
        hh[e] = hb; ll[e] = f2bf(x - bf2f(hb));
    }
#pragma unroll
    for (int e = 0; e < 4; ++e) {
        float x = b[e] * sc; short hb = f2bf(x);
        hh[4 + e] = hb; ll[4 + e] = f2bf(x - bf2f(hb));
    }
}

__global__ __launch_bounds__(512, 2) void sdpa_fused(
    const float* __restrict__ Qg, const float* __restrict__ Kg,
    const float* __restrict__ Vg, float* __restrict__ Og, float* __restrict__ Pg)
{
    const int i = blockIdx.x;
    const int g = i & 7;
    const int j = i >> 3;             // 0..63
    const int b = 2 * g + (j >> 5);
    const int jj = j & 31;
    const int qb = (j < 32) ? jj : (jj ^ 1);   // EQUAL-LENGTH pairing (R16)
    const int q0 = qb * QB;

    const int tid = threadIdx.x;
    const int lane = tid & 63;
    const int wave = tid >> 6;        // 0..7
    const int wr = wave & 3;          // row band: rows wr*16..wr*16+15
    const int h  = wave >> 2;         // col half: n in {2h, 2h+1}
    const int n0 = 2 * h;
    const int lo = lane & 15;
    const int hi = lane >> 4;
    const bool kStager = (wave < 4);
    const int stid = kStager ? tid : (tid - 256);   // 0..255 in role group
    const int sr = stid >> 4;
    const int sc_ = (stid & 15) * 4;
    const int vr = (stid >> 4) * 4;

    __shared__ short Khi[2][KT * KLD];   // 18.4 KB
    __shared__ short Vt [3][DIM * VLD];  // 27.6 KB
    __shared__ short Pb [2][QB * PBLD];  // 18.4 KB
    __shared__ float lS [2][QB];         // 0.5 KB

    const float* qB = Qg + (size_t)b * SEQ * DIM;
    const float* kB = Kg + (size_t)b * SEQ * DIM;
    const float* vB = Vg + (size_t)b * SEQ * DIM;

    bf16x8 qa0h, qa0l, qa1h, qa1l;
    {
        const float* qr = &qB[(size_t)(q0 + wr * 16 + lo) * DIM + hi * 8];
        split8(*(const f32x4*)qr,        *(const f32x4*)(qr + 4),  0.125f, qa0h, qa0l);
        split8(*(const f32x4*)(qr + 32), *(const f32x4*)(qr + 36), 0.125f, qa1h, qa1l);
    }

    const int nkt = qb + 1;

    auto loadK = [&](f32x4* kp, int kt) {
#pragma unroll
        for (int ii = 0; ii < 4; ++ii)
            kp[ii] = *(const f32x4*)&kB[(size_t)(kt * KT + sr + 16 * ii) * DIM + sc_];
    };
    auto loadV = [&](f32x4* vp, int kt) {
#pragma unroll
        for (int ii = 0; ii < 4; ++ii)
            vp[ii] = *(const f32x4*)&vB[(size_t)(kt * KT + vr + ii) * DIM + sc_];
    };
    auto stageKhi = [&](int buf, const f32x4* kp) {
#pragma unroll
        for (int ii = 0; ii < 4; ++ii) {
            short4v hh;
#pragma unroll
            for (int e = 0; e < 4; ++e) hh[e] = f2bf(kp[ii][e]);
            *(short4v*)&Khi[buf][(sr + 16 * ii) * KLD + sc_] = hh;
        }
    };
    auto stageVt = [&](int buf, const f32x4* vp) {
#pragma unroll
        for (int e = 0; e < 4; ++e) {
            short4v tv;
#pragma unroll
            for (int ii = 0; ii < 4; ++ii) tv[ii] = f2bf(vp[ii][e]);
            *(short4v*)&Vt[buf][(sc_ + e) * VLD + vr] = tv;
        }
    };

    // ================ phase 1: l partial sums (own col half) ================
    float rl[4] = {0.f, 0.f, 0.f, 0.f};
    {
        f32x4 kp[4];
        if (kStager) {
            loadK(kp, 0);
            stageKhi(0, kp);
            if (nkt > 1) loadK(kp, 1);
        }
        BAR();
        for (int kt = 0; kt < nkt; ++kt) {
            const int cur = kt & 1;
            if (kStager && kt + 1 < nkt) {
                stageKhi(cur ^ 1, kp);
                if (kt + 2 < nkt) loadK(kp, kt + 2);
            }
#pragma unroll
            for (int nn = 0; nn < 2; ++nn) {
                const int n = n0 + nn;
                if (kt == qb && n > wr) continue;   // wave-uniform skip
                bf16x8 kh0 = *(const bf16x8*)&Khi[cur][(16 * n + lo) * KLD + hi * 8];
                bf16x8 kh1 = *(const bf16x8*)&Khi[cur][(16 * n + lo) * KLD + 32 + hi * 8];
                f32x4 acc = {0.f, 0.f, 0.f, 0.f};
                __builtin_amdgcn_s_setprio(1);
                acc = __builtin_amdgcn_mfma_f32_16x16x32_bf16(qa0h, kh0, acc, 0, 0, 0);
                acc = __builtin_amdgcn_mfma_f32_16x16x32_bf16(qa1h, kh1, acc, 0, 0, 0);
                __builtin_amdgcn_s_setprio(0);
                if (kt < qb) {
#pragma unroll
                    for (int jx = 0; jx < 4; ++jx) rl[jx] += __expf(acc[jx]);
                } else {
                    const int col = 16 * n + lo;
#pragma unroll
                    for (int jx = 0; jx < 4; ++jx)
                        if (col <= wr * 16 + hi * 4 + jx) rl[jx] += __expf(acc[jx]);
                }
            }
            BAR();
        }
    }
    // merge the two col-half partials -> il
#pragma unroll
    for (int m = 1; m <= 8; m <<= 1)
#pragma unroll
        for (int jx = 0; jx < 4; ++jx) rl[jx] += __shfl_xor(rl[jx], m, 16);
    if (lo == 0) {
#pragma unroll
        for (int jx = 0; jx < 4; ++jx)
            lS[h][wr * 16 + hi * 4 + jx] = rl[jx];
    }
    BAR();
    float il[4];
#pragma unroll
    for (int jx = 0; jx < 4; ++jx) {
        const int row = wr * 16 + hi * 4 + jx;
        il[jx] = 1.0f / (lS[0][row] + lS[1][row]);
    }

    // ===== phase 2: P = exp(S)*il direct-store + pipelined O = P*V =====
    f32x4 o2[2];
#pragma unroll
    for (int nn = 0; nn < 2; ++nn) { o2[nn][0] = 0.f; o2[nn][1] = 0.f; o2[nn][2] = 0.f; o2[nn][3] = 0.f; }

    float* prowBase = &Pg[((size_t)(b * SEQ) + q0 + wr * 16 + hi * 4) * SEQ + lo];

    {
        f32x4 kp[4], vp[4];
        if (kStager) {
            loadK(kp, 0); stageKhi(0, kp);
            if (nkt > 1) loadK(kp, 1);
        } else {
            loadV(vp, 0); stageVt(0, vp);
            if (nkt > 1) loadV(vp, 1);
        }
        BAR();

        int vstg = 1, vprev = 2;
        for (int kt = 0; kt < nkt; ++kt) {
            const int cur = kt & 1;
            const int pcur = kt & 1;
            if (kt + 1 < nkt) {
                if (kStager) {
                    stageKhi(cur ^ 1, kp);
                    if (kt + 2 < nkt) loadK(kp, kt + 2);
                } else {
                    stageVt(vstg, vp);
                    if (kt + 2 < nkt) loadV(vp, kt + 2);
                }
            }
            // ---- PV(kt-1): partner-wave Pb/Vt ordered by previous BAR ----
            if (kt > 0) {
                bf16x8 pa0 = *(const bf16x8*)&Pb[pcur ^ 1][(wr * 16 + lo) * PBLD + hi * 8];
                bf16x8 pa1 = *(const bf16x8*)&Pb[pcur ^ 1][(wr * 16 + lo) * PBLD + 32 + hi * 8];
                __builtin_amdgcn_s_setprio(1);
#pragma unroll
                for (int nn = 0; nn < 2; ++nn) {
                    const int n = n0 + nn;
                    bf16x8 vb0 = *(const bf16x8*)&Vt[vprev][(16 * n + lo) * VLD + hi * 8];
                    bf16x8 vb1 = *(const bf16x8*)&Vt[vprev][(16 * n + lo) * VLD + 32 + hi * 8];
                    o2[nn] = __builtin_amdgcn_mfma_f32_16x16x32_bf16(pa0, vb0, o2[nn], 0, 0, 0);
                    o2[nn] = __builtin_amdgcn_mfma_f32_16x16x32_bf16(pa1, vb1, o2[nn], 0, 0, 0);
                }
                __builtin_amdgcn_s_setprio(0);
            }
            // ---- QKT(kt) (Q-side compensated): P = exp(S)*il ----
#pragma unroll
            for (int nn = 0; nn < 2; ++nn) {
                const int n = n0 + nn;
                const bool fm = (kt == qb) && (n > wr);   // wave-uniform
                f32x4 acc = {0.f, 0.f, 0.f, 0.f};
                if (!fm) {
                    bf16x8 kh0 = *(const bf16x8*)&Khi[cur][(16 * n + lo) * KLD + hi * 8];
                    bf16x8 kh1 = *(const bf16x8*)&Khi[cur][(16 * n + lo) * KLD + 32 + hi * 8];
                    __builtin_amdgcn_s_setprio(1);
                    acc = __builtin_amdgcn_mfma_f32_16x16x32_bf16(qa0h, kh0, acc, 0, 0, 0);
                    acc = __builtin_amdgcn_mfma_f32_16x16x32_bf16(qa1h, kh1, acc, 0, 0, 0);
                    acc = __builtin_amdgcn_mfma_f32_16x16x32_bf16(qa0l, kh0, acc, 0, 0, 0);
                    acc = __builtin_amdgcn_mfma_f32_16x16x32_bf16(qa1l, kh1, acc, 0, 0, 0);
                    __builtin_amdgcn_s_setprio(0);
                }
                const int col = 16 * n + lo;
                float* pcol = prowBase + kt * KT + 16 * n;
#pragma unroll
                for (int jx = 0; jx < 4; ++jx) {
                    const int row = wr * 16 + hi * 4 + jx;
                    const float p = (!fm && (kt < qb || col <= row)) ? __expf(acc[jx]) * il[jx] : 0.f;
                    pcol[(size_t)jx * SEQ] = p;
                    Pb[pcur][row * PBLD + col] = f2bf(p);
                }
            }
            BAR();
            vprev = (vprev == 2) ? 0 : vprev + 1;
            vstg  = (vstg  == 2) ? 0 : vstg  + 1;
        }
        // ---- epilogue PV(nkt-1): ordered by the loop's final BAR ----
        {
            const int pl = (nkt - 1) & 1;
            const int vl = (nkt - 1) % 3;
            bf16x8 pa0 = *(const bf16x8*)&Pb[pl][(wr * 16 + lo) * PBLD + hi * 8];
            bf16x8 pa1 = *(const bf16x8*)&Pb[pl][(wr * 16 + lo) * PBLD + 32 + hi * 8];
#pragma unroll
            for (int nn = 0; nn < 2; ++nn) {
                const int n = n0 + nn;
                bf16x8 vb0 = *(const bf16x8*)&Vt[vl][(16 * n + lo) * VLD + hi * 8];
                bf16x8 vb1 = *(const bf16x8*)&Vt[vl][(16 * n + lo) * VLD + 32 + hi * 8];
                o2[nn] = __builtin_amdgcn_mfma_f32_16x16x32_bf16(pa0, vb0, o2[nn], 0, 0, 0);
                o2[nn] = __builtin_amdgcn_mfma_f32_16x16x32_bf16(pa1, vb1, o2[nn], 0, 0, 0);
            }
        }
    }

    // ---- zero-fill fully-masked column tiles (exact 0 == ref underflow) ----
    {
        const int r = tid >> 3;
        const int c8 = (tid & 7) * 8;
        float* rowp = &Pg[((size_t)(b * SEQ) + q0 + r) * SEQ + c8];
        const f32x4 z = {0.f, 0.f, 0.f, 0.f};
        for (int cb = nkt * KT; cb < SEQ; cb += KT) {
            *(f32x4*)&rowp[cb] = z;
            *(f32x4*)&rowp[cb + 4] = z;
        }
    }
    // ---- O (already normalized; own col half), fp32 ----
    {
        float* og = &Og[((size_t)(b * SEQ) + q0 + wr * 16 + hi * 4) * DIM + lo];
#pragma unroll
        for (int jx = 0; jx < 4; ++jx)
#pragma unroll
            for (int nn = 0; nn < 2; ++nn)
                og[jx * DIM + (n0 + nn) * 16] = o2[nn][jx];
    }
}

extern "C" void kernel_launch(void* const* d_in, const int* in_sizes, int n_in,
                              void* d_out, int out_size, void* d_ws, size_t ws_size,
                              hipStream_t stream) {
    const float* q = (const float*)d_in[0];
    const float* k = (const float*)d_in[1];
    const float* v = (const float*)d_in[2];
    float* out  = (float*)d_out;                        // [B,T,D] fp32
    float* smqk = out + (size_t)BATCHES * SEQ * DIM;    // [B,T,T] fp32

    sdpa_fused<<<NQB * BATCHES, 512, 0, stream>>>(q, k, v, out, smqk);
}

// Round 17
// 98.226 us; speedup vs baseline: 1.1348x; 1.1348x over previous
//
#include <hip/hip_runtime.h>
#include <hip/hip_bf16.h>

// SDPA, causal, b=16 t=2048 d=64. Outputs FP32: d_out = [ out | sm_qk ].
// R17 = R15 + phase-1 KT=128 (LDS overlay): rounds sum across co-resident
// blocks (R16 evidence), so cut round count. Phase 1 stages a 128-row K tile
// (dbuf, 36.9 KB) overlaid on phase-2's Vt/Pb region; 2 k-tiles per barrier
// round -> phase-1 rounds halve. Phase 2 = R15 verbatim (8-wave, T15
// pipeline, role-split staging, Q-side-compensated QK^T, lgkm barriers).
// Pairing: sum-balanced (c, 31-c) as R15.

#define BATCHES 16
#define SEQ 2048
#define DIM 64
#define QB 64
#define KT 64
#define KT1 128
#define NQB (SEQ / QB) /* 32 */
#define KLD 72
#define VLD 72
#define PBLD 72

#define BAR() do { asm volatile("s_waitcnt lgkmcnt(0)" ::: "memory"); \
                   __builtin_amdgcn_s_barrier(); } while (0)

typedef __attribute__((ext_vector_type(8))) short bf16x8;
typedef __attribute__((ext_vector_type(4))) short short4v;
typedef __attribute__((ext_vector_type(4))) float f32x4;

static __device__ __forceinline__ short f2bf(float f) {
    return __builtin_bit_cast(short, __float2bfloat16(f));
}
static __device__ __forceinline__ float bf2f(short s) {
    unsigned int u = ((unsigned int)(unsigned short)s) << 16;
    return __builtin_bit_cast(float, u);
}
static __device__ __forceinline__ void split8(f32x4 a, f32x4 b, float sc,
                                              bf16x8& hh, bf16x8& ll) {
#pragma unroll
    for (int e = 0; e < 4; ++e) {
        float x = a[e] * sc; short hb = f2bf(x);
        hh[e] = hb; ll[e] = f2bf(x - bf2f(hb));
    }
#pragma unroll
    for (int e = 0; e < 4; ++e) {
        float x = b[e] * sc; short hb = f2bf(x);
        hh[4 + e] = hb; ll[4 + e] = f2bf(x - bf2f(hb));
    }
}

// LDS budget (bytes): phase2 Khi 18432 | Vt 27648 | Pb 18432 | lS 512 = 65024
// phase1 K1 [2][128*72]*2B = 36864 overlays [Khi..Vt] region.
#define SMEM_BYTES 65024

__global__ __launch_bounds__(512, 2) void sdpa_fused(
    const float* __restrict__ Qg, const float* __restrict__ Kg,
    const float* __restrict__ Vg, float* __restrict__ Og, float* __restrict__ Pg)
{
    const int i = blockIdx.x;
    const int g = i & 7;
    const int j = i >> 3;             // 0..63
    const int b = 2 * g + (j >> 5);
    const int jj = j & 31;
    const int qb = (j < 32) ? jj : (31 - jj);   // sum-balanced pairing (R15)
    const int q0 = qb * QB;

    const int tid = threadIdx.x;
    const int lane = tid & 63;
    const int wave = tid >> 6;        // 0..7
    const int wr = wave & 3;          // row band: rows wr*16..wr*16+15
    const int h  = wave >> 2;         // col half
    const int lo = lane & 15;
    const int hi = lane >> 4;
    const bool kStager = (wave < 4);
    const int stid = kStager ? tid : (tid - 256);
    const int sr = stid >> 4;
    const int sc_ = (stid & 15) * 4;
    const int vr = (stid >> 4) * 4;
    // phase-1 staging (all 512 threads): rows s1r+32*ii, col s1c
    const int s1r = tid >> 4;         // 0..31
    const int s1c = (tid & 15) * 4;

    __shared__ __align__(16) char smem[SMEM_BYTES];
    short (*Khi)[KT * KLD]  = reinterpret_cast<short (*)[KT * KLD]>(smem);            // [2]
    short (*Vt)[DIM * VLD]  = reinterpret_cast<short (*)[DIM * VLD]>(smem + 18432);   // [3]
    short (*Pb)[QB * PBLD]  = reinterpret_cast<short (*)[QB * PBLD]>(smem + 46080);   // [2]
    float (*lS)[QB]         = reinterpret_cast<float (*)[QB]>(smem + 64512);          // [2]
    short (*K1)[KT1 * KLD]  = reinterpret_cast<short (*)[KT1 * KLD]>(smem);           // [2] overlay

    const float* qB = Qg + (size_t)b * SEQ * DIM;
    const float* kB = Kg + (size_t)b * SEQ * DIM;
    const float* vB = Vg + (size_t)b * SEQ * DIM;

    bf16x8 qa0h, qa0l, qa1h, qa1l;
    {
        const float* qr = &qB[(size_t)(q0 + wr * 16 + lo) * DIM + hi * 8];
        split8(*(const f32x4*)qr,        *(const f32x4*)(qr + 4),  0.125f, qa0h, qa0l);
        split8(*(const f32x4*)(qr + 32), *(const f32x4*)(qr + 36), 0.125f, qa1h, qa1l);
    }

    const int nkt = qb + 1;

    // ============ phase 1: l partial sums, KT1=128 per round ============
    float rl[4] = {0.f, 0.f, 0.f, 0.f};
    {
        const int nkt1 = (nkt + 1) >> 1;        // 128-wide rounds
        auto loadK1 = [&](f32x4* kp, int t) {
#pragma unroll
            for (int ii = 0; ii < 4; ++ii)
                kp[ii] = *(const f32x4*)&kB[(size_t)(t * KT1 + s1r + 32 * ii) * DIM + s1c];
        };
        auto stageK1 = [&](int buf, const f32x4* kp) {
#pragma unroll
            for (int ii = 0; ii < 4; ++ii) {
                short4v hh;
#pragma unroll
                for (int e = 0; e < 4; ++e) hh[e] = f2bf(kp[ii][e]);
                *(short4v*)&K1[buf][(s1r + 32 * ii) * KLD + s1c] = hh;
            }
        };
        f32x4 kp[4];
        loadK1(kp, 0);
        stageK1(0, kp);
        if (nkt1 > 1) loadK1(kp, 1);
        BAR();
        const int bandMax = q0 + wr * 16 + 15;  // wave-uniform
        for (int t = 0; t < nkt1; ++t) {
            const int cur = t & 1;
            if (t + 1 < nkt1) {
                stageK1(cur ^ 1, kp);
                if (t + 2 < nkt1) loadK1(kp, t + 2);
            }
            const int base = t * KT1;
#pragma unroll
            for (int nn = 0; nn < 4; ++nn) {
                const int n = 4 * h + nn;       // col group 0..7 in the 128-tile
                const int cbase = base + 16 * n;
                if (cbase > bandMax) continue;  // wave-uniform skip (incl. >qb tiles)
                bf16x8 kh0 = *(const bf16x8*)&K1[cur][(16 * n + lo) * KLD + hi * 8];
                bf16x8 kh1 = *(const bf16x8*)&K1[cur][(16 * n + lo) * KLD + 32 + hi * 8];
                f32x4 acc = {0.f, 0.f, 0.f, 0.f};
                __builtin_amdgcn_s_setprio(1);
                acc = __builtin_amdgcn_mfma_f32_16x16x32_bf16(qa0h, kh0, acc, 0, 0, 0);
                acc = __builtin_amdgcn_mfma_f32_16x16x32_bf16(qa1h, kh1, acc, 0, 0, 0);
                __builtin_amdgcn_s_setprio(0);
                if (cbase + 15 <= q0 + wr * 16) {   // fully unmasked (wave-uniform)
#pragma unroll
                    for (int jx = 0; jx < 4; ++jx) rl[jx] += __expf(acc[jx]);
                } else {
                    const int col = cbase + lo;
#pragma unroll
                    for (int jx = 0; jx < 4; ++jx)
                        if (col <= q0 + wr * 16 + hi * 4 + jx) rl[jx] += __expf(acc[jx]);
                }
            }
            BAR();
        }
    }
    // merge the two col-half partials -> il
#pragma unroll
    for (int m = 1; m <= 8; m <<= 1)
#pragma unroll
        for (int jx = 0; jx < 4; ++jx) rl[jx] += __shfl_xor(rl[jx], m, 16);
    if (lo == 0) {
#pragma unroll
        for (int jx = 0; jx < 4; ++jx)
            lS[h][wr * 16 + hi * 4 + jx] = rl[jx];
    }
    BAR();
    float il[4];
#pragma unroll
    for (int jx = 0; jx < 4; ++jx) {
        const int row = wr * 16 + hi * 4 + jx;
        il[jx] = 1.0f / (lS[0][row] + lS[1][row]);
    }
    BAR();   // all waves done reading lS before phase 2 overwrites smem

    // ===== phase 2: P = exp(S)*il direct-store + pipelined O = P*V =====
    const int n0 = 2 * h;
    f32x4 o2[2];
#pragma unroll
    for (int nn = 0; nn < 2; ++nn) { o2[nn][0] = 0.f; o2[nn][1] = 0.f; o2[nn][2] = 0.f; o2[nn][3] = 0.f; }

    float* prowBase = &Pg[((size_t)(b * SEQ) + q0 + wr * 16 + hi * 4) * SEQ + lo];

    auto loadK = [&](f32x4* kp, int kt) {
#pragma unroll
        for (int ii = 0; ii < 4; ++ii)
            kp[ii] = *(const f32x4*)&kB[(size_t)(kt * KT + sr + 16 * ii) * DIM + sc_];
    };
    auto loadV = [&](f32x4* vp, int kt) {
#pragma unroll
        for (int ii = 0; ii < 4; ++ii)
            vp[ii] = *(const f32x4*)&vB[(size_t)(kt * KT + vr + ii) * DIM + sc_];
    };
    auto stageKhi = [&](int buf, const f32x4* kp) {
#pragma unroll
        for (int ii = 0; ii < 4; ++ii) {
            short4v hh;
#pragma unroll
            for (int e = 0; e < 4; ++e) hh[e] = f2bf(kp[ii][e]);
            *(short4v*)&Khi[buf][(sr + 16 * ii) * KLD + sc_] = hh;
        }
    };
    auto stageVt = [&](int buf, const f32x4* vp) {
#pragma unroll
        for (int e = 0; e < 4; ++e) {
            short4v tv;
#pragma unroll
            for (int ii = 0; ii < 4; ++ii) tv[ii] = f2bf(vp[ii][e]);
            *(short4v*)&Vt[buf][(sc_ + e) * VLD + vr] = tv;
        }
    };

    {
        f32x4 kp[4], vp[4];
        if (kStager) {
            loadK(kp, 0); stageKhi(0, kp);
            if (nkt > 1) loadK(kp, 1);
        } else {
            loadV(vp, 0); stageVt(0, vp);
            if (nkt > 1) loadV(vp, 1);
        }
        BAR();

        int vstg = 1, vprev = 2;
        for (int kt = 0; kt < nkt; ++kt) {
            const int cur = kt & 1;
            const int pcur = kt & 1;
            if (kt + 1 < nkt) {
                if (kStager) {
                    stageKhi(cur ^ 1, kp);
                    if (kt + 2 < nkt) loadK(kp, kt + 2);
                } else {
                    stageVt(vstg, vp);
                    if (kt + 2 < nkt) loadV(vp, kt + 2);
                }
            }
            // ---- PV(kt-1): partner-wave Pb/Vt ordered by previous BAR ----
            if (kt > 0) {
                bf16x8 pa0 = *(const bf16x8*)&Pb[pcur ^ 1][(wr * 16 + lo) * PBLD + hi * 8];
                bf16x8 pa1 = *(const bf16x8*)&Pb[pcur ^ 1][(wr * 16 + lo) * PBLD + 32 + hi * 8];
                __builtin_amdgcn_s_setprio(1);
#pragma unroll
                for (int nn = 0; nn < 2; ++nn) {
                    const int n = n0 + nn;
                    bf16x8 vb0 = *(const bf16x8*)&Vt[vprev][(16 * n + lo) * VLD + hi * 8];
                    bf16x8 vb1 = *(const bf16x8*)&Vt[vprev][(16 * n + lo) * VLD + 32 + hi * 8];
                    o2[nn] = __builtin_amdgcn_mfma_f32_16x16x32_bf16(pa0, vb0, o2[nn], 0, 0, 0);
                    o2[nn] = __builtin_amdgcn_mfma_f32_16x16x32_bf16(pa1, vb1, o2[nn], 0, 0, 0);
                }
                __builtin_amdgcn_s_setprio(0);
            }
            // ---- QKT(kt) (Q-side compensated): P = exp(S)*il ----
#pragma unroll
            for (int nn = 0; nn < 2; ++nn) {
                const int n = n0 + nn;
                const bool fm = (kt == qb) && (n > wr);   // wave-uniform
                f32x4 acc = {0.f, 0.f, 0.f, 0.f};
                if (!fm) {
                    bf16x8 kh0 = *(const bf16x8*)&Khi[cur][(16 * n + lo) * KLD + hi * 8];
                    bf16x8 kh1 = *(const bf16x8*)&Khi[cur][(16 * n + lo) * KLD + 32 + hi * 8];
                    __builtin_amdgcn_s_setprio(1);
                    acc = __builtin_amdgcn_mfma_f32_16x16x32_bf16(qa0h, kh0, acc, 0, 0, 0);
                    acc = __builtin_amdgcn_mfma_f32_16x16x32_bf16(qa1h, kh1, acc, 0, 0, 0);
                    acc = __builtin_amdgcn_mfma_f32_16x16x32_bf16(qa0l, kh0, acc, 0, 0, 0);
                    acc = __builtin_amdgcn_mfma_f32_16x16x32_bf16(qa1l, kh1, acc, 0, 0, 0);
                    __builtin_amdgcn_s_setprio(0);
                }
                const int col = 16 * n + lo;
                float* pcol = prowBase + kt * KT + 16 * n;
#pragma unroll
                for (int jx = 0; jx < 4; ++jx) {
                    const int row = wr * 16 + hi * 4 + jx;
                    const float p = (!fm && (kt < qb || col <= row)) ? __expf(acc[jx]) * il[jx] : 0.f;
                    pcol[(size_t)jx * SEQ] = p;
                    Pb[pcur][row * PBLD + col] = f2bf(p);
                }
            }
            BAR();
            vprev = (vprev == 2) ? 0 : vprev + 1;
            vstg  = (vstg  == 2) ? 0 : vstg  + 1;
        }
        // ---- epilogue PV(nkt-1): ordered by the loop's final BAR ----
        {
            const int pl = (nkt - 1) & 1;
            const int vl = (nkt - 1) % 3;
            bf16x8 pa0 = *(const bf16x8*)&Pb[pl][(wr * 16 + lo) * PBLD + hi * 8];
            bf16x8 pa1 = *(const bf16x8*)&Pb[pl][(wr * 16 + lo) * PBLD + 32 + hi * 8];
#pragma unroll
            for (int nn = 0; nn < 2; ++nn) {
                const int n = n0 + nn;
                bf16x8 vb0 = *(const bf16x8*)&Vt[vl][(16 * n + lo) * VLD + hi * 8];
                bf16x8 vb1 = *(const bf16x8*)&Vt[vl][(16 * n + lo) * VLD + 32 + hi * 8];
                o2[nn] = __builtin_amdgcn_mfma_f32_16x16x32_bf16(pa0, vb0, o2[nn], 0, 0, 0);
                o2[nn] = __builtin_amdgcn_mfma_f32_16x16x32_bf16(pa1, vb1, o2[nn], 0, 0, 0);
            }
        }
    }

    // ---- zero-fill fully-masked column tiles (exact 0 == ref underflow) ----
    {
        const int r = tid >> 3;
        const int c8 = (tid & 7) * 8;
        float* rowp = &Pg[((size_t)(b * SEQ) + q0 + r) * SEQ + c8];
        const f32x4 z = {0.f, 0.f, 0.f, 0.f};
        for (int cb = nkt * KT; cb < SEQ; cb += KT) {
            *(f32x4*)&rowp[cb] = z;
            *(f32x4*)&rowp[cb + 4] = z;
        }
    }
    // ---- O (already normalized; own col half), fp32 ----
    {
        float* og = &Og[((size_t)(b * SEQ) + q0 + wr * 16 + hi * 4) * DIM + lo];
#pragma unroll
        for (int jx = 0; jx < 4; ++jx)
#pragma unroll
            for (int nn = 0; nn < 2; ++nn)
                og[jx * DIM + (n0 + nn) * 16] = o2[nn][jx];
    }
}

extern "C" void kernel_launch(void* const* d_in, const int* in_sizes, int n_in,
                              void* d_out, int out_size, void* d_ws, size_t ws_size,
                              hipStream_t stream) {
    const float* q = (const float*)d_in[0];
    const float* k = (const float*)d_in[1];
    const float* v = (const float*)d_in[2];
    float* out  = (float*)d_out;                        // [B,T,D] fp32
    float* smqk = out + (size_t)BATCHES * SEQ * DIM;    // [B,T,T] fp32

    sdpa_fused<<<NQB * BATCHES, 512, 0, stream>>>(q, k, v, out, smqk);
}